// Round 7
// baseline (366.301 us; speedup 1.0000x reference)
//
#include <hip/hip_runtime.h>
#include <hip/hip_bf16.h>

#define S_LEN 2048
#define D_DIM 64
#define QT    64
#define KT    64
#define NTHR  256
#define NKT   (S_LEN / KT)          // 32
#define NBLK  1024                  // 32 q-tiles * 32 bh = 4 blocks/CU
#define PROB_ELEMS 4194304LL        // 2*16*2048*64

typedef float        f32x4  __attribute__((ext_vector_type(4)));
typedef int          i32x4  __attribute__((ext_vector_type(4)));
typedef unsigned int u32x4  __attribute__((ext_vector_type(4)));
typedef short        bf16x8 __attribute__((ext_vector_type(8)));

__device__ __forceinline__ unsigned short f2bf(float f) {
    return __builtin_bit_cast(unsigned short, __float2bfloat16(f));
}
// 16B-chunk XOR swizzle for 128B-row LDS tiles
__device__ __forceinline__ int swzc(int row, int ch) {
    return ch ^ ((row ^ (row >> 3)) & 7);
}
__device__ __forceinline__ float4 scale4(float4 v, float s) {
    v.x *= s; v.y *= s; v.z *= s; v.w *= s; return v;
}
__device__ __forceinline__ u32x4 packbf(float4 a, float4 b) {
    u32x4 r;
    r[0] = (unsigned)f2bf(a.x) | ((unsigned)f2bf(a.y) << 16);
    r[1] = (unsigned)f2bf(a.z) | ((unsigned)f2bf(a.w) << 16);
    r[2] = (unsigned)f2bf(b.x) | ((unsigned)f2bf(b.y) << 16);
    r[3] = (unsigned)f2bf(b.z) | ((unsigned)f2bf(b.w) << 16);
    return r;
}
// single-instruction packed bf16 convert (RNE), gfx950
__device__ __forceinline__ unsigned cvtpk(float lo, float hi) {
    unsigned r;
    asm("v_cvt_pk_bf16_f32 %0, %1, %2" : "=v"(r) : "v"(lo), "v"(hi));
    return r;
}
// async global->LDS, 16B per lane; dst must be wave-uniform base
__device__ __forceinline__ void glds16(const unsigned* g, unsigned char* l) {
    __builtin_amdgcn_global_load_lds(
        (const __attribute__((address_space(1))) unsigned*)g,
        (__attribute__((address_space(3))) unsigned*)(void*)l, 16, 0, 0);
}

// -------------------------------------------------------------------------
__global__ void mask_probe_kernel(const unsigned int* __restrict__ m,
                                  int* __restrict__ flag) {
    unsigned int v = m[threadIdx.x];
    unsigned long long ok = __ballot(v <= 1u);
    if (threadIdx.x == 0) *flag = (ok == ~0ULL) ? 1 : 0;
}

// -------------------------------------------------------------------------
// One-shot prep: K -> bf16 tile images (8KB per (bh,kt), swizzled, byte-
// identical to the LDS image), V -> transposed [d][k] bf16 tile images.
// -------------------------------------------------------------------------
#define KPART 524288   // 32bh * 2048k * 8ch
#define VPART 65536    // 32bh * 32kt * 64d
__global__ __launch_bounds__(256)
void kv_prep(const float* __restrict__ Kg, const float* __restrict__ Vg,
             unsigned* __restrict__ Kbf, unsigned* __restrict__ Vtb) {
    int tid = blockIdx.x * 256 + threadIdx.x;
    if (tid < KPART) {
        int ch = tid & 7, rowg = tid >> 3;          // rowg = bh*2048 + k
        const float* src = Kg + (long long)rowg * D_DIM + ch * 8;
        float4 a = *(const float4*)src, b = *(const float4*)(src + 4);
        int bh = rowg >> 11, k = rowg & 2047, kt = k >> 6, row = k & 63;
        unsigned* dst = Kbf + ((unsigned)(bh * NKT + kt) << 11)
                            + row * 32 + swzc(row, ch) * 4;
        *(u32x4*)dst = packbf(a, b);
    } else if (tid < KPART + VPART) {
        int idx = tid - KPART;
        int d = idx & 63, kt = (idx >> 6) & 31, bh = idx >> 11;
        const float* vb = Vg + (long long)(bh * S_LEN + kt * KT) * D_DIM + d;
        unsigned* tile = Vtb + ((unsigned)(bh * NKT + kt) << 11) + d * 32;
        #pragma unroll
        for (int ci = 0; ci < 8; ++ci) {
            u32x4 o;
            #pragma unroll
            for (int s = 0; s < 4; ++s) {
                float lo = vb[(ci * 8 + 2 * s) * D_DIM];
                float hi = vb[(ci * 8 + 2 * s + 1) * D_DIM];
                o[s] = (unsigned)f2bf(lo) | ((unsigned)f2bf(hi) << 16);
            }
            *(u32x4*)(tile + swzc(d, ci) * 4) = o;
        }
    }
}

// Geometry (swapped QK): mfma(A=K, B=Q) -> lane holds
//   P[k = kt*64 + 16n + 4g + r][q = w*16 + c],  c=lane&15, g=lane>>4, r=0..3
// PV: mfma(A=P(q rows of wave w), B=Vt(d)) -> prob[q=w*16+4g+r][d=16df+c].
// Q pre-scaled by 0.125 at staging -> attn = __expf(acc) directly.

#define LOAD_MBITS(DST, KTV)                                                \
    { unsigned bz = 0u;                                                     \
      _Pragma("unroll")                                                     \
      for (int n = 0; n < 4; ++n) {                                         \
        unsigned idx = rowoff + (unsigned)((KTV) * KT + n * 16 + 4 * g);    \
        if (mask32) {                                                       \
            i32x4 m4 = *(const i32x4*)(((const int*)maskB) + idx);          \
            bz |= ((m4[0] ? 1u : 0u) | (m4[1] ? 2u : 0u) |                  \
                   (m4[2] ? 4u : 0u) | (m4[3] ? 8u : 0u)) << (n * 4);       \
        } else {                                                            \
            unsigned mb = *(const unsigned*)(maskB + idx);                  \
            bz |= (((mb & 0xffu) ? 1u : 0u) | ((mb & 0xff00u) ? 2u : 0u) |  \
                   ((mb & 0xff0000u) ? 4u : 0u) |                           \
                   ((mb & 0xff000000u) ? 8u : 0u)) << (n * 4);              \
        } }                                                                 \
      (DST) = bz; }

#define LOAD_BITS2(DST, KTV)                                                \
    { if (useWS) (DST) = (unsigned)bitsWS[bitbase + (unsigned)(KTV) * NTHR];\
      else LOAD_MBITS(DST, KTV) }

#define PH1_TILE(KS, BITS)                                                  \
    { unsigned bb = (BITS);                                                 \
      _Pragma("unroll")                                                     \
      for (int n = 0; n < 4; ++n) {                                         \
        int rowk = n * 16 + c;                                              \
        bf16x8 kf0 = *(const bf16x8*)((KS) + rowk * 128 + swzc(rowk, g) * 16);     \
        bf16x8 kf1 = *(const bf16x8*)((KS) + rowk * 128 + swzc(rowk, 4 + g) * 16); \
        f32x4 acc = {0.f, 0.f, 0.f, 0.f};                                   \
        acc = __builtin_amdgcn_mfma_f32_16x16x32_bf16(kf0, qf0, acc, 0, 0, 0); \
        acc = __builtin_amdgcn_mfma_f32_16x16x32_bf16(kf1, qf1, acc, 0, 0, 0); \
        unsigned mb = bb >> (n * 4);                                        \
        psum += (mb & 1u) ? 0.f : __expf(acc[0]);                           \
        psum += (mb & 2u) ? 0.f : __expf(acc[1]);                           \
        psum += (mb & 4u) ? 0.f : __expf(acc[2]);                           \
        psum += (mb & 8u) ? 0.f : __expf(acc[3]);                           \
      } }

#define PH2_TILE(KS, VT, BITS, KTV)                                         \
    { unsigned bb = (BITS);                                                 \
      _Pragma("unroll")                                                     \
      for (int n = 0; n < 4; ++n) {                                         \
        int rowk = n * 16 + c;                                              \
        bf16x8 kf0 = *(const bf16x8*)((KS) + rowk * 128 + swzc(rowk, g) * 16);     \
        bf16x8 kf1 = *(const bf16x8*)((KS) + rowk * 128 + swzc(rowk, 4 + g) * 16); \
        f32x4 acc = {0.f, 0.f, 0.f, 0.f};                                   \
        acc = __builtin_amdgcn_mfma_f32_16x16x32_bf16(kf0, qf0, acc, 0, 0, 0); \
        acc = __builtin_amdgcn_mfma_f32_16x16x32_bf16(kf1, qf1, acc, 0, 0, 0); \
        unsigned mb = bb >> (n * 4);                                        \
        f32x4 ev;                                                           \
        ev[0] = (mb & 1u) ? 0.f : __expf(acc[0]) * rinv;                    \
        ev[1] = (mb & 2u) ? 0.f : __expf(acc[1]) * rinv;                    \
        ev[2] = (mb & 4u) ? 0.f : __expf(acc[2]) * rinv;                    \
        ev[3] = (mb & 8u) ? 0.f : __expf(acc[3]) * rinv;                    \
        unsigned idx0 = rowoff + (unsigned)((KTV) * KT + n * 16 + 4 * g);   \
        __builtin_nontemporal_store(ev, (f32x4*)(attnOut + idx0));          \
        uint2 pkv; pkv.x = cvtpk(ev[0], ev[1]); pkv.y = cvtpk(ev[2], ev[3]);\
        int kloc = n * 16 + 4 * g;                                          \
        *(uint2*)(Ps + ql * 128 + swzc(ql, kloc >> 3) * 16 + (kloc & 7) * 2) = pkv; \
      }                                                                     \
      { bf16x8 pa0 = *(const bf16x8*)(Ps + ql * 128 + swzc(ql, g) * 16);    \
        bf16x8 pa1 = *(const bf16x8*)(Ps + ql * 128 + swzc(ql, 4 + g) * 16);\
        __builtin_amdgcn_s_setprio(1);                                      \
        _Pragma("unroll")                                                   \
        for (int df = 0; df < 4; ++df) {                                    \
            int d = df * 16 + c;                                            \
            bf16x8 vb0 = *(const bf16x8*)((VT) + d * 128 + swzc(d, g) * 16);     \
            bf16x8 vb1 = *(const bf16x8*)((VT) + d * 128 + swzc(d, 4 + g) * 16); \
            pacc[df] = __builtin_amdgcn_mfma_f32_16x16x32_bf16(pa0, vb0, pacc[df], 0, 0, 0); \
            pacc[df] = __builtin_amdgcn_mfma_f32_16x16x32_bf16(pa1, vb1, pacc[df], 0, 0, 0); \
        }                                                                   \
        __builtin_amdgcn_s_setprio(0); } }

// -------------------------------------------------------------------------
// Main kernel (prep path): K/V staged via global_load_lds from pre-built
// tile images. 1 barrier per k-tile, double-buffered.
// -------------------------------------------------------------------------
__global__ __launch_bounds__(NTHR, 4)
void attn_fused_glds(const float* __restrict__ Qg,
                     const unsigned* __restrict__ Kbf,
                     const unsigned* __restrict__ Vtb,
                     const unsigned char* __restrict__ maskB,
                     const int* __restrict__ flagp,
                     unsigned short* __restrict__ bitsWS, int useWS,
                     float* __restrict__ attnOut, float* __restrict__ probOut) {
    __shared__ unsigned char sm[40960];
    unsigned char* Ks0 = sm;
    unsigned char* Ks1 = sm + 8192;
    unsigned char* Vt0 = sm + 16384;
    unsigned char* Vt1 = sm + 24576;
    unsigned char* Ps  = sm + 32768;

    const int t = threadIdx.x;
    const int lane = t & 63, w = t >> 6, c = lane & 15, g = lane >> 4;

    const int orig = blockIdx.x;
    const int virt = (orig & 7) * 128 + (orig >> 3);   // XCD swizzle
    const int qt = virt & 31, bh = virt >> 5;
    const int mask32 = *flagp;

    const int qrowbase = bh * S_LEN + qt * QT;
    const int ql = w * 16 + c;
    const unsigned rowoff = (unsigned)(qrowbase + ql) * (unsigned)S_LEN;
    const unsigned bitbase = (unsigned)virt * NKT * NTHR + (unsigned)t;
    const unsigned ktile0 = (unsigned)(bh * NKT) << 11;   // u32 index

    // per-thread glds source offsets (u32) and wave-uniform LDS dest (bytes)
    const int f0u = t * 4, f1u = (NTHR + t) * 4;
    const int dst0 = (t & ~63) * 16, dst1 = (NTHR + (t & ~63)) * 16;

    // ---- stage Q (pre-scaled by 1/8) into Ps, keep fragments ----
    #pragma unroll
    for (int i = 0; i < 2; ++i) {
        int flat = i * NTHR + t, row = flat >> 3, ch = flat & 7;
        const float* src = Qg + (qrowbase + row) * D_DIM + ch * 8;
        float4 a = *(const float4*)src, b = *(const float4*)(src + 4);
        *(u32x4*)(Ps + row * 128 + swzc(row, ch) * 16) =
            packbf(scale4(a, 0.125f), scale4(b, 0.125f));
    }
    __syncthreads();
    bf16x8 qf0 = *(const bf16x8*)(Ps + ql * 128 + swzc(ql, g) * 16);
    bf16x8 qf1 = *(const bf16x8*)(Ps + ql * 128 + swzc(ql, 4 + g) * 16);

    // =================== PHASE 1: rowsum + mask bits ===================
    float psum = 0.f;
    unsigned bA, bB;
    {
        const unsigned* kp = Kbf + ktile0;
        glds16(kp + f0u, Ks0 + dst0);
        glds16(kp + f1u, Ks0 + dst1);
    }
    LOAD_MBITS(bA, 0)

    for (int j = 0; j < NKT / 2; ++j) {
        const int ktA = 2 * j, ktB = 2 * j + 1;
        __syncthreads();   // Ks(cur) loaded; Ks(nxt) free
        {
            const unsigned* kp = Kbf + ktile0 + (unsigned)ktB * 2048;
            glds16(kp + f0u, Ks1 + dst0);
            glds16(kp + f1u, Ks1 + dst1);
        }
        LOAD_MBITS(bB, ktB)
        PH1_TILE(Ks0, bA)
        if (useWS) bitsWS[bitbase + (unsigned)ktA * NTHR] = (unsigned short)bA;

        __syncthreads();
        if (j + 1 < NKT / 2) {
            const unsigned* kp = Kbf + ktile0 + (unsigned)(ktA + 2) * 2048;
            glds16(kp + f0u, Ks0 + dst0);
            glds16(kp + f1u, Ks0 + dst1);
            LOAD_MBITS(bA, ktA + 2)
        }
        PH1_TILE(Ks1, bB)
        if (useWS) bitsWS[bitbase + (unsigned)ktB * NTHR] = (unsigned short)bB;
    }

    float s = psum;
    s += __shfl_xor(s, 16, 64);
    s += __shfl_xor(s, 32, 64);
    const float rinv = 1.0f / s;

    // =================== PHASE 2: attn + PV ===================
    f32x4 pacc[4];
    #pragma unroll
    for (int d = 0; d < 4; ++d) pacc[d] = (f32x4){0.f, 0.f, 0.f, 0.f};

    {
        const unsigned* kp = Kbf + ktile0;
        const unsigned* vp = Vtb + ktile0;
        glds16(kp + f0u, Ks0 + dst0); glds16(kp + f1u, Ks0 + dst1);
        glds16(vp + f0u, Vt0 + dst0); glds16(vp + f1u, Vt0 + dst1);
    }
    LOAD_BITS2(bA, 0)

    for (int j = 0; j < NKT / 2; ++j) {
        const int ktA = 2 * j, ktB = 2 * j + 1;
        __syncthreads();   // buf0 ready; buf1 free
        {
            const unsigned* kp = Kbf + ktile0 + (unsigned)ktB * 2048;
            const unsigned* vp = Vtb + ktile0 + (unsigned)ktB * 2048;
            glds16(kp + f0u, Ks1 + dst0); glds16(kp + f1u, Ks1 + dst1);
            glds16(vp + f0u, Vt1 + dst0); glds16(vp + f1u, Vt1 + dst1);
        }
        LOAD_BITS2(bB, ktB)
        PH2_TILE(Ks0, Vt0, bA, ktA)

        __syncthreads();   // buf1 ready; buf0 free
        if (j + 1 < NKT / 2) {
            const unsigned* kp = Kbf + ktile0 + (unsigned)(ktA + 2) * 2048;
            const unsigned* vp = Vtb + ktile0 + (unsigned)(ktA + 2) * 2048;
            glds16(kp + f0u, Ks0 + dst0); glds16(kp + f1u, Ks0 + dst1);
            glds16(vp + f0u, Vt0 + dst0); glds16(vp + f1u, Vt0 + dst1);
            LOAD_BITS2(bA, ktA + 2)
        }
        PH2_TILE(Ks1, Vt1, bB, ktB)
    }

    #pragma unroll
    for (int df = 0; df < 4; ++df)
        #pragma unroll
        for (int r = 0; r < 4; ++r) {
            int qe = w * 16 + g * 4 + r;
            probOut[(long long)(qrowbase + qe) * D_DIM + df * 16 + c] = pacc[df][r];
        }
}

// -------------------------------------------------------------------------
// Fallback (register staging, R5 structure) if ws too small for prep.
// -------------------------------------------------------------------------
#define LOAD_K(KP, KTV)                                                     \
    { _Pragma("unroll")                                                     \
      for (int i = 0; i < 2; ++i) {                                         \
        int flat = i * NTHR + t, row = flat >> 3, ch = flat & 7;            \
        const float* src = Kg + (kbase + (KTV) * KT + row) * D_DIM + ch * 8;\
        float4 a = *(const float4*)src, b = *(const float4*)(src + 4);      \
        KP[i] = packbf(a, b);                                               \
      } }
#define STAGE_K(KS, KP)                                                     \
    { _Pragma("unroll")                                                     \
      for (int i = 0; i < 2; ++i) {                                         \
        int flat = i * NTHR + t, row = flat >> 3, ch = flat & 7;            \
        *(u32x4*)((KS) + row * 128 + swzc(row, ch) * 16) = KP[i];           \
      } }
#define LOAD_V(VP, KTV)                                                     \
    { const float* src = Vg + (kbase + (KTV) * KT + k0v) * D_DIM + dgv * 8; \
      float4 a = *(const float4*)src, b = *(const float4*)(src + 4);        \
      float4 e4 = *(const float4*)(src + D_DIM);                            \
      float4 f4 = *(const float4*)(src + D_DIM + 4);                        \
      VP[0] = (unsigned)f2bf(a.x) | ((unsigned)f2bf(e4.x) << 16);           \
      VP[1] = (unsigned)f2bf(a.y) | ((unsigned)f2bf(e4.y) << 16);           \
      VP[2] = (unsigned)f2bf(a.z) | ((unsigned)f2bf(e4.z) << 16);           \
      VP[3] = (unsigned)f2bf(a.w) | ((unsigned)f2bf(e4.w) << 16);           \
      VP[4] = (unsigned)f2bf(b.x) | ((unsigned)f2bf(f4.x) << 16);           \
      VP[5] = (unsigned)f2bf(b.y) | ((unsigned)f2bf(f4.y) << 16);           \
      VP[6] = (unsigned)f2bf(b.z) | ((unsigned)f2bf(f4.z) << 16);           \
      VP[7] = (unsigned)f2bf(b.w) | ((unsigned)f2bf(f4.w) << 16); }
#define STAGE_V(VT, VP)                                                     \
    { _Pragma("unroll")                                                     \
      for (int jj = 0; jj < 8; ++jj) {                                      \
        int d = dgv * 8 + jj;                                               \
        *(unsigned*)((VT) + d * 128 + swzc(d, k0v >> 3) * 16 + (k0v & 7) * 2) = VP[jj]; \
      } }

__global__ __launch_bounds__(NTHR, 4)
void attn_fused_reg(const float* __restrict__ Qg, const float* __restrict__ Kg,
                    const float* __restrict__ Vg,
                    const unsigned char* __restrict__ maskB,
                    const int* __restrict__ flagp,
                    unsigned short* __restrict__ bitsWS, int useWS,
                    float* __restrict__ attnOut, float* __restrict__ probOut) {
    __shared__ unsigned char sm[40960];
    unsigned char* Ks0 = sm;
    unsigned char* Ks1 = sm + 8192;
    unsigned char* Vt0 = sm + 16384;
    unsigned char* Vt1 = sm + 24576;
    unsigned char* Ps  = sm + 32768;

    const int t = threadIdx.x;
    const int lane = t & 63, w = t >> 6, c = lane & 15, g = lane >> 4;

    const int orig = blockIdx.x;
    const int virt = (orig & 7) * 128 + (orig >> 3);
    const int qt = virt & 31, bh = virt >> 5;
    const int mask32 = *flagp;

    const int qrowbase = bh * S_LEN + qt * QT;
    const int kbase = bh * S_LEN;
    const int ql = w * 16 + c;
    const unsigned rowoff = (unsigned)(qrowbase + ql) * (unsigned)S_LEN;
    const unsigned bitbase = (unsigned)virt * NKT * NTHR + (unsigned)t;
    const int dgv = t & 7, k0v = (t >> 3) * 2;

    #pragma unroll
    for (int i = 0; i < 2; ++i) {
        int flat = i * NTHR + t, row = flat >> 3, ch = flat & 7;
        const float* src = Qg + (qrowbase + row) * D_DIM + ch * 8;
        float4 a = *(const float4*)src, b = *(const float4*)(src + 4);
        *(u32x4*)(Ps + row * 128 + swzc(row, ch) * 16) =
            packbf(scale4(a, 0.125f), scale4(b, 0.125f));
    }
    __syncthreads();
    bf16x8 qf0 = *(const bf16x8*)(Ps + ql * 128 + swzc(ql, g) * 16);
    bf16x8 qf1 = *(const bf16x8*)(Ps + ql * 128 + swzc(ql, 4 + g) * 16);
    __syncthreads();

    float psum = 0.f;
    u32x4 kpA[2], kpB[2];
    unsigned bA, bB;
    LOAD_K(kpA, 0)
    LOAD_MBITS(bA, 0)

    for (int j = 0; j < NKT / 2; ++j) {
        const int ktA = 2 * j, ktB = 2 * j + 1;
        STAGE_K(Ks0, kpA)
        LOAD_K(kpB, ktB)
        LOAD_MBITS(bB, ktB)
        __syncthreads();
        PH1_TILE(Ks0, bA)
        if (useWS) bitsWS[bitbase + (unsigned)ktA * NTHR] = (unsigned short)bA;
        STAGE_K(Ks1, kpB)
        if (j + 1 < NKT / 2) {
            LOAD_K(kpA, ktA + 2)
            LOAD_MBITS(bA, ktA + 2)
        }
        __syncthreads();
        PH1_TILE(Ks1, bB)
        if (useWS) bitsWS[bitbase + (unsigned)ktB * NTHR] = (unsigned short)bB;
    }

    float s = psum;
    s += __shfl_xor(s, 16, 64);
    s += __shfl_xor(s, 32, 64);
    const float rinv = 1.0f / s;

    f32x4 pacc[4];
    #pragma unroll
    for (int d = 0; d < 4; ++d) pacc[d] = (f32x4){0.f, 0.f, 0.f, 0.f};

    unsigned vpA[8], vpB[8];
    LOAD_K(kpA, 0)
    LOAD_V(vpA, 0)
    LOAD_BITS2(bA, 0)
    __syncthreads();

    for (int j = 0; j < NKT / 2; ++j) {
        const int ktA = 2 * j, ktB = 2 * j + 1;
        STAGE_K(Ks0, kpA)
        STAGE_V(Vt0, vpA)
        LOAD_K(kpB, ktB)
        LOAD_V(vpB, ktB)
        LOAD_BITS2(bB, ktB)
        __syncthreads();
        PH2_TILE(Ks0, Vt0, bA, ktA)
        STAGE_K(Ks1, kpB)
        STAGE_V(Vt1, vpB)
        if (j + 1 < NKT / 2) {
            LOAD_K(kpA, ktA + 2)
            LOAD_V(vpA, ktA + 2)
            LOAD_BITS2(bA, ktA + 2)
        }
        __syncthreads();
        PH2_TILE(Ks1, Vt1, bB, ktB)
    }

    #pragma unroll
    for (int df = 0; df < 4; ++df)
        #pragma unroll
        for (int r = 0; r < 4; ++r) {
            int qe = w * 16 + g * 4 + r;
            probOut[(long long)(qrowbase + qe) * D_DIM + df * 16 + c] = pacc[df][r];
        }
}

// -------------------------------------------------------------------------
extern "C" void kernel_launch(void* const* d_in, const int* in_sizes, int n_in,
                              void* d_out, int out_size, void* d_ws, size_t ws_size,
                              hipStream_t stream) {
    const float* Q = (const float*)d_in[0];
    const float* K = (const float*)d_in[1];
    const float* V = (const float*)d_in[2];
    const unsigned char* mask = (const unsigned char*)d_in[3];

    float* prob = (float*)d_out;
    float* attn = (float*)d_out + PROB_ELEMS;

    const size_t bits_bytes = (size_t)NBLK * NKT * NTHR * 2ull;   // 16.78 MB
    const size_t kbf_bytes  = 8388608ull;                          // per tensor
    int* flag = (int*)d_ws;
    unsigned short* bitsWS = (unsigned short*)((char*)d_ws + 256);
    unsigned* Kbf = (unsigned*)((char*)d_ws + 256 + bits_bytes);
    unsigned* Vtb = (unsigned*)((char*)d_ws + 256 + bits_bytes + kbf_bytes);

    const int useWS   = (ws_size >= 256 + bits_bytes) ? 1 : 0;
    const int usePrep = (ws_size >= 256 + bits_bytes + 2 * kbf_bytes) ? 1 : 0;

    mask_probe_kernel<<<1, 64, 0, stream>>>((const unsigned int*)mask, flag);
    if (usePrep) {
        kv_prep<<<(KPART + VPART) / 256, 256, 0, stream>>>(K, V, Kbf, Vtb);
        attn_fused_glds<<<NBLK, NTHR, 0, stream>>>(Q, Kbf, Vtb, mask, flag,
                                                   bitsWS, useWS, attn, prob);
    } else {
        attn_fused_reg<<<NBLK, NTHR, 0, stream>>>(Q, K, V, mask, flag,
                                                  bitsWS, useWS, attn, prob);
    }
}

// Round 8
// 363.811 us; speedup vs baseline: 1.0068x; 1.0068x over previous
//
#include <hip/hip_runtime.h>
#include <hip/hip_bf16.h>

#define S_LEN 2048
#define D_DIM 64
#define QT    64
#define KT    64
#define NTHR  256
#define NKT   (S_LEN / KT)          // 32
#define NBLK  1024                  // 32 q-tiles * 32 bh = 4 blocks/CU
#define PROB_ELEMS 4194304LL        // 2*16*2048*64

typedef float        f32x4  __attribute__((ext_vector_type(4)));
typedef int          i32x4  __attribute__((ext_vector_type(4)));
typedef unsigned int u32x4  __attribute__((ext_vector_type(4)));
typedef short        bf16x8 __attribute__((ext_vector_type(8)));

__device__ __forceinline__ unsigned short f2bf(float f) {
    return __builtin_bit_cast(unsigned short, __float2bfloat16(f));
}
// 16B-chunk XOR swizzle for 128B-row LDS tiles
__device__ __forceinline__ int swzc(int row, int ch) {
    return ch ^ ((row ^ (row >> 3)) & 7);
}
__device__ __forceinline__ float4 scale4(float4 v, float s) {
    v.x *= s; v.y *= s; v.z *= s; v.w *= s; return v;
}
__device__ __forceinline__ u32x4 packbf(float4 a, float4 b) {
    u32x4 r;
    r[0] = (unsigned)f2bf(a.x) | ((unsigned)f2bf(a.y) << 16);
    r[1] = (unsigned)f2bf(a.z) | ((unsigned)f2bf(a.w) << 16);
    r[2] = (unsigned)f2bf(b.x) | ((unsigned)f2bf(b.y) << 16);
    r[3] = (unsigned)f2bf(b.z) | ((unsigned)f2bf(b.w) << 16);
    return r;
}
// single-instruction packed bf16 convert (RNE), gfx950
__device__ __forceinline__ unsigned cvtpk(float lo, float hi) {
    unsigned r;
    asm("v_cvt_pk_bf16_f32 %0, %1, %2" : "=v"(r) : "v"(lo), "v"(hi));
    return r;
}
// async global->LDS, 16B per lane; dst must be wave-uniform base
__device__ __forceinline__ void glds16(const unsigned* g, unsigned char* l) {
    __builtin_amdgcn_global_load_lds(
        (const __attribute__((address_space(1))) unsigned*)g,
        (__attribute__((address_space(3))) unsigned*)(void*)l, 16, 0, 0);
}

// -------------------------------------------------------------------------
__global__ void mask_probe_kernel(const unsigned int* __restrict__ m,
                                  int* __restrict__ flag) {
    unsigned int v = m[threadIdx.x];
    unsigned long long ok = __ballot(v <= 1u);
    if (threadIdx.x == 0) *flag = (ok == ~0ULL) ? 1 : 0;
}

// -------------------------------------------------------------------------
// One-shot prep: K -> bf16 tile images (8KB per (bh,kt), swizzled, byte-
// identical to the LDS image), V -> transposed [d][k] bf16 tile images.
// -------------------------------------------------------------------------
#define KPART 524288   // 32bh * 2048k * 8ch
#define VPART 65536    // 32bh * 32kt * 64d
__global__ __launch_bounds__(256)
void kv_prep(const float* __restrict__ Kg, const float* __restrict__ Vg,
             unsigned* __restrict__ Kbf, unsigned* __restrict__ Vtb) {
    int tid = blockIdx.x * 256 + threadIdx.x;
    if (tid < KPART) {
        int ch = tid & 7, rowg = tid >> 3;          // rowg = bh*2048 + k
        const float* src = Kg + (long long)rowg * D_DIM + ch * 8;
        float4 a = *(const float4*)src, b = *(const float4*)(src + 4);
        int bh = rowg >> 11, k = rowg & 2047, kt = k >> 6, row = k & 63;
        unsigned* dst = Kbf + ((unsigned)(bh * NKT + kt) << 11)
                            + row * 32 + swzc(row, ch) * 4;
        *(u32x4*)dst = packbf(a, b);
    } else if (tid < KPART + VPART) {
        int idx = tid - KPART;
        int d = idx & 63, kt = (idx >> 6) & 31, bh = idx >> 11;
        const float* vb = Vg + (long long)(bh * S_LEN + kt * KT) * D_DIM + d;
        unsigned* tile = Vtb + ((unsigned)(bh * NKT + kt) << 11) + d * 32;
        #pragma unroll
        for (int ci = 0; ci < 8; ++ci) {
            u32x4 o;
            #pragma unroll
            for (int s = 0; s < 4; ++s) {
                float lo = vb[(ci * 8 + 2 * s) * D_DIM];
                float hi = vb[(ci * 8 + 2 * s + 1) * D_DIM];
                o[s] = (unsigned)f2bf(lo) | ((unsigned)f2bf(hi) << 16);
            }
            *(u32x4*)(tile + swzc(d, ci) * 4) = o;
        }
    }
}

// Geometry (swapped QK): mfma(A=K, B=Q) -> lane holds
//   P[k = kt*64 + 16n + 4g + r][q = w*16 + c],  c=lane&15, g=lane>>4, r=0..3
// PV: mfma(A=P(q rows of wave w), B=Vt(d)) -> prob[q=w*16+4g+r][d=16df+c].
// Q pre-scaled by 0.125 at staging -> attn = __expf(acc) directly.

#define LOAD_MBITS(DST, KTV)                                                \
    { unsigned bz = 0u;                                                     \
      _Pragma("unroll")                                                     \
      for (int n = 0; n < 4; ++n) {                                         \
        unsigned idx = rowoff + (unsigned)((KTV) * KT + n * 16 + 4 * g);    \
        if (mask32) {                                                       \
            i32x4 m4 = *(const i32x4*)(((const int*)maskB) + idx);          \
            bz |= ((m4[0] ? 1u : 0u) | (m4[1] ? 2u : 0u) |                  \
                   (m4[2] ? 4u : 0u) | (m4[3] ? 8u : 0u)) << (n * 4);       \
        } else {                                                            \
            unsigned mb = *(const unsigned*)(maskB + idx);                  \
            bz |= (((mb & 0xffu) ? 1u : 0u) | ((mb & 0xff00u) ? 2u : 0u) |  \
                   ((mb & 0xff0000u) ? 4u : 0u) |                           \
                   ((mb & 0xff000000u) ? 8u : 0u)) << (n * 4);              \
        } }                                                                 \
      (DST) = bz; }

#define LOAD_BITS2(DST, KTV)                                                \
    { if (useWS) (DST) = (unsigned)bitsWS[bitbase + (unsigned)(KTV) * NTHR];\
      else LOAD_MBITS(DST, KTV) }

#define PH1_TILE(KS, BITS)                                                  \
    { unsigned bb = (BITS);                                                 \
      _Pragma("unroll")                                                     \
      for (int n = 0; n < 4; ++n) {                                         \
        int rowk = n * 16 + c;                                              \
        bf16x8 kf0 = *(const bf16x8*)((KS) + rowk * 128 + swzc(rowk, g) * 16);     \
        bf16x8 kf1 = *(const bf16x8*)((KS) + rowk * 128 + swzc(rowk, 4 + g) * 16); \
        f32x4 acc = {0.f, 0.f, 0.f, 0.f};                                   \
        acc = __builtin_amdgcn_mfma_f32_16x16x32_bf16(kf0, qf0, acc, 0, 0, 0); \
        acc = __builtin_amdgcn_mfma_f32_16x16x32_bf16(kf1, qf1, acc, 0, 0, 0); \
        unsigned mb = bb >> (n * 4);                                        \
        psum += (mb & 1u) ? 0.f : __expf(acc[0]);                           \
        psum += (mb & 2u) ? 0.f : __expf(acc[1]);                           \
        psum += (mb & 4u) ? 0.f : __expf(acc[2]);                           \
        psum += (mb & 8u) ? 0.f : __expf(acc[3]);                           \
      } }

#define PH2_TILE(KS, VT, BITS, KTV)                                         \
    { unsigned bb = (BITS);                                                 \
      _Pragma("unroll")                                                     \
      for (int n = 0; n < 4; ++n) {                                         \
        int rowk = n * 16 + c;                                              \
        bf16x8 kf0 = *(const bf16x8*)((KS) + rowk * 128 + swzc(rowk, g) * 16);     \
        bf16x8 kf1 = *(const bf16x8*)((KS) + rowk * 128 + swzc(rowk, 4 + g) * 16); \
        f32x4 acc = {0.f, 0.f, 0.f, 0.f};                                   \
        acc = __builtin_amdgcn_mfma_f32_16x16x32_bf16(kf0, qf0, acc, 0, 0, 0); \
        acc = __builtin_amdgcn_mfma_f32_16x16x32_bf16(kf1, qf1, acc, 0, 0, 0); \
        unsigned mb = bb >> (n * 4);                                        \
        f32x4 ev;                                                           \
        ev[0] = (mb & 1u) ? 0.f : __expf(acc[0]) * rinv;                    \
        ev[1] = (mb & 2u) ? 0.f : __expf(acc[1]) * rinv;                    \
        ev[2] = (mb & 4u) ? 0.f : __expf(acc[2]) * rinv;                    \
        ev[3] = (mb & 8u) ? 0.f : __expf(acc[3]) * rinv;                    \
        unsigned idx0 = rowoff + (unsigned)((KTV) * KT + n * 16 + 4 * g);   \
        __builtin_nontemporal_store(ev, (f32x4*)(attnOut + idx0));          \
        uint2 pkv; pkv.x = cvtpk(ev[0], ev[1]); pkv.y = cvtpk(ev[2], ev[3]);\
        int kloc = n * 16 + 4 * g;                                          \
        *(uint2*)(Ps + ql * 128 + swzc(ql, kloc >> 3) * 16 + (kloc & 7) * 2) = pkv; \
      }                                                                     \
      { bf16x8 pa0 = *(const bf16x8*)(Ps + ql * 128 + swzc(ql, g) * 16);    \
        bf16x8 pa1 = *(const bf16x8*)(Ps + ql * 128 + swzc(ql, 4 + g) * 16);\
        __builtin_amdgcn_s_setprio(1);                                      \
        _Pragma("unroll")                                                   \
        for (int df = 0; df < 4; ++df) {                                    \
            int d = df * 16 + c;                                            \
            bf16x8 vb0 = *(const bf16x8*)((VT) + d * 128 + swzc(d, g) * 16);     \
            bf16x8 vb1 = *(const bf16x8*)((VT) + d * 128 + swzc(d, 4 + g) * 16); \
            pacc[df] = __builtin_amdgcn_mfma_f32_16x16x32_bf16(pa0, vb0, pacc[df], 0, 0, 0); \
            pacc[df] = __builtin_amdgcn_mfma_f32_16x16x32_bf16(pa1, vb1, pacc[df], 0, 0, 0); \
        }                                                                   \
        __builtin_amdgcn_s_setprio(0); } }

// -------------------------------------------------------------------------
// Main kernel (prep path): K/V staged via global_load_lds from pre-built
// tile images. 1 barrier per k-tile, double-buffered.
// -------------------------------------------------------------------------
__global__ __launch_bounds__(NTHR, 4)
void attn_fused_glds(const float* __restrict__ Qg,
                     const unsigned* __restrict__ Kbf,
                     const unsigned* __restrict__ Vtb,
                     const unsigned char* __restrict__ maskB,
                     const int* __restrict__ flagp,
                     unsigned short* __restrict__ bitsWS, int useWS,
                     float* __restrict__ attnOut, float* __restrict__ probOut) {
    __shared__ unsigned char sm[40960];
    unsigned char* Ks0 = sm;
    unsigned char* Ks1 = sm + 8192;
    unsigned char* Vt0 = sm + 16384;
    unsigned char* Vt1 = sm + 24576;
    unsigned char* Ps  = sm + 32768;

    const int t = threadIdx.x;
    const int lane = t & 63, w = t >> 6, c = lane & 15, g = lane >> 4;

    const int orig = blockIdx.x;
    const int virt = (orig & 7) * 128 + (orig >> 3);   // XCD swizzle
    const int qt = virt & 31, bh = virt >> 5;
    const int mask32 = *flagp;

    const int qrowbase = bh * S_LEN + qt * QT;
    const int ql = w * 16 + c;
    const unsigned rowoff = (unsigned)(qrowbase + ql) * (unsigned)S_LEN;
    const unsigned bitbase = (unsigned)virt * NKT * NTHR + (unsigned)t;
    const unsigned ktile0 = (unsigned)(bh * NKT) << 11;   // u32 index

    // per-thread glds source offsets (u32) and wave-uniform LDS dest (bytes)
    const int f0u = t * 4, f1u = (NTHR + t) * 4;
    const int dst0 = (t & ~63) * 16, dst1 = (NTHR + (t & ~63)) * 16;

    // ---- stage Q (pre-scaled by 1/8) into Ps, keep fragments ----
    #pragma unroll
    for (int i = 0; i < 2; ++i) {
        int flat = i * NTHR + t, row = flat >> 3, ch = flat & 7;
        const float* src = Qg + (qrowbase + row) * D_DIM + ch * 8;
        float4 a = *(const float4*)src, b = *(const float4*)(src + 4);
        *(u32x4*)(Ps + row * 128 + swzc(row, ch) * 16) =
            packbf(scale4(a, 0.125f), scale4(b, 0.125f));
    }
    __syncthreads();
    bf16x8 qf0 = *(const bf16x8*)(Ps + ql * 128 + swzc(ql, g) * 16);
    bf16x8 qf1 = *(const bf16x8*)(Ps + ql * 128 + swzc(ql, 4 + g) * 16);

    // =================== PHASE 1: rowsum + mask bits ===================
    float psum = 0.f;
    unsigned bA, bB;
    {
        const unsigned* kp = Kbf + ktile0;
        glds16(kp + f0u, Ks0 + dst0);
        glds16(kp + f1u, Ks0 + dst1);
    }
    LOAD_MBITS(bA, 0)

    for (int j = 0; j < NKT / 2; ++j) {
        const int ktA = 2 * j, ktB = 2 * j + 1;
        __syncthreads();   // Ks(cur) loaded; Ks(nxt) free
        {
            const unsigned* kp = Kbf + ktile0 + (unsigned)ktB * 2048;
            glds16(kp + f0u, Ks1 + dst0);
            glds16(kp + f1u, Ks1 + dst1);
        }
        LOAD_MBITS(bB, ktB)
        PH1_TILE(Ks0, bA)
        if (useWS) bitsWS[bitbase + (unsigned)ktA * NTHR] = (unsigned short)bA;

        __syncthreads();
        if (j + 1 < NKT / 2) {
            const unsigned* kp = Kbf + ktile0 + (unsigned)(ktA + 2) * 2048;
            glds16(kp + f0u, Ks0 + dst0);
            glds16(kp + f1u, Ks0 + dst1);
            LOAD_MBITS(bA, ktA + 2)
        }
        PH1_TILE(Ks1, bB)
        if (useWS) bitsWS[bitbase + (unsigned)ktB * NTHR] = (unsigned short)bB;
    }

    float s = psum;
    s += __shfl_xor(s, 16, 64);
    s += __shfl_xor(s, 32, 64);
    const float rinv = 1.0f / s;

    // =================== PHASE 2: attn + PV ===================
    f32x4 pacc[4];
    #pragma unroll
    for (int d = 0; d < 4; ++d) pacc[d] = (f32x4){0.f, 0.f, 0.f, 0.f};

    {
        const unsigned* kp = Kbf + ktile0;
        const unsigned* vp = Vtb + ktile0;
        glds16(kp + f0u, Ks0 + dst0); glds16(kp + f1u, Ks0 + dst1);
        glds16(vp + f0u, Vt0 + dst0); glds16(vp + f1u, Vt0 + dst1);
    }
    LOAD_BITS2(bA, 0)

    for (int j = 0; j < NKT / 2; ++j) {
        const int ktA = 2 * j, ktB = 2 * j + 1;
        __syncthreads();   // buf0 ready; buf1 free
        {
            const unsigned* kp = Kbf + ktile0 + (unsigned)ktB * 2048;
            const unsigned* vp = Vtb + ktile0 + (unsigned)ktB * 2048;
            glds16(kp + f0u, Ks1 + dst0); glds16(kp + f1u, Ks1 + dst1);
            glds16(vp + f0u, Vt1 + dst0); glds16(vp + f1u, Vt1 + dst1);
        }
        LOAD_BITS2(bB, ktB)
        PH2_TILE(Ks0, Vt0, bA, ktA)

        __syncthreads();   // buf1 ready; buf0 free
        if (j + 1 < NKT / 2) {
            const unsigned* kp = Kbf + ktile0 + (unsigned)(ktA + 2) * 2048;
            const unsigned* vp = Vtb + ktile0 + (unsigned)(ktA + 2) * 2048;
            glds16(kp + f0u, Ks0 + dst0); glds16(kp + f1u, Ks0 + dst1);
            glds16(vp + f0u, Vt0 + dst0); glds16(vp + f1u, Vt0 + dst1);
            LOAD_BITS2(bA, ktA + 2)
        }
        PH2_TILE(Ks1, Vt1, bB, ktB)
    }

    #pragma unroll
    for (int df = 0; df < 4; ++df)
        #pragma unroll
        for (int r = 0; r < 4; ++r) {
            int qe = w * 16 + g * 4 + r;
            probOut[(long long)(qrowbase + qe) * D_DIM + df * 16 + c] = pacc[df][r];
        }
}

// -------------------------------------------------------------------------
// Fallback (register staging, R5 structure) if ws too small for prep.
// -------------------------------------------------------------------------
#define LOAD_K(KP, KTV)                                                     \
    { _Pragma("unroll")                                                     \
      for (int i = 0; i < 2; ++i) {                                         \
        int flat = i * NTHR + t, row = flat >> 3, ch = flat & 7;            \
        const float* src = Kg + (kbase + (KTV) * KT + row) * D_DIM + ch * 8;\
        float4 a = *(const float4*)src, b = *(const float4*)(src + 4);      \
        KP[i] = packbf(a, b);                                               \
      } }
#define STAGE_K(KS, KP)                                                     \
    { _Pragma("unroll")                                                     \
      for (int i = 0; i < 2; ++i) {                                         \
        int flat = i * NTHR + t, row = flat >> 3, ch = flat & 7;            \
        *(u32x4*)((KS) + row * 128 + swzc(row, ch) * 16) = KP[i];           \
      } }
#define LOAD_V(VP, KTV)                                                     \
    { const float* src = Vg + (kbase + (KTV) * KT + k0v) * D_DIM + dgv * 8; \
      float4 a = *(const float4*)src, b = *(const float4*)(src + 4);        \
      float4 e4 = *(const float4*)(src + D_DIM);                            \
      float4 f4 = *(const float4*)(src + D_DIM + 4);                        \
      VP[0] = (unsigned)f2bf(a.x) | ((unsigned)f2bf(e4.x) << 16);           \
      VP[1] = (unsigned)f2bf(a.y) | ((unsigned)f2bf(e4.y) << 16);           \
      VP[2] = (unsigned)f2bf(a.z) | ((unsigned)f2bf(e4.z) << 16);           \
      VP[3] = (unsigned)f2bf(a.w) | ((unsigned)f2bf(e4.w) << 16);           \
      VP[4] = (unsigned)f2bf(b.x) | ((unsigned)f2bf(f4.x) << 16);           \
      VP[5] = (unsigned)f2bf(b.y) | ((unsigned)f2bf(f4.y) << 16);           \
      VP[6] = (unsigned)f2bf(b.z) | ((unsigned)f2bf(f4.z) << 16);           \
      VP[7] = (unsigned)f2bf(b.w) | ((unsigned)f2bf(f4.w) << 16); }
#define STAGE_V(VT, VP)                                                     \
    { _Pragma("unroll")                                                     \
      for (int jj = 0; jj < 8; ++jj) {                                      \
        int d = dgv * 8 + jj;                                               \
        *(unsigned*)((VT) + d * 128 + swzc(d, k0v >> 3) * 16 + (k0v & 7) * 2) = VP[jj]; \
      } }

__global__ __launch_bounds__(NTHR, 4)
void attn_fused_reg(const float* __restrict__ Qg, const float* __restrict__ Kg,
                    const float* __restrict__ Vg,
                    const unsigned char* __restrict__ maskB,
                    const int* __restrict__ flagp,
                    unsigned short* __restrict__ bitsWS, int useWS,
                    float* __restrict__ attnOut, float* __restrict__ probOut) {
    __shared__ unsigned char sm[40960];
    unsigned char* Ks0 = sm;
    unsigned char* Ks1 = sm + 8192;
    unsigned char* Vt0 = sm + 16384;
    unsigned char* Vt1 = sm + 24576;
    unsigned char* Ps  = sm + 32768;

    const int t = threadIdx.x;
    const int lane = t & 63, w = t >> 6, c = lane & 15, g = lane >> 4;

    const int orig = blockIdx.x;
    const int virt = (orig & 7) * 128 + (orig >> 3);
    const int qt = virt & 31, bh = virt >> 5;
    const int mask32 = *flagp;

    const int qrowbase = bh * S_LEN + qt * QT;
    const int kbase = bh * S_LEN;
    const int ql = w * 16 + c;
    const unsigned rowoff = (unsigned)(qrowbase + ql) * (unsigned)S_LEN;
    const unsigned bitbase = (unsigned)virt * NKT * NTHR + (unsigned)t;
    const int dgv = t & 7, k0v = (t >> 3) * 2;

    #pragma unroll
    for (int i = 0; i < 2; ++i) {
        int flat = i * NTHR + t, row = flat >> 3, ch = flat & 7;
        const float* src = Qg + (qrowbase + row) * D_DIM + ch * 8;
        float4 a = *(const float4*)src, b = *(const float4*)(src + 4);
        *(u32x4*)(Ps + row * 128 + swzc(row, ch) * 16) =
            packbf(scale4(a, 0.125f), scale4(b, 0.125f));
    }
    __syncthreads();
    bf16x8 qf0 = *(const bf16x8*)(Ps + ql * 128 + swzc(ql, g) * 16);
    bf16x8 qf1 = *(const bf16x8*)(Ps + ql * 128 + swzc(ql, 4 + g) * 16);
    __syncthreads();

    float psum = 0.f;
    u32x4 kpA[2], kpB[2];
    unsigned bA, bB;
    LOAD_K(kpA, 0)
    LOAD_MBITS(bA, 0)

    for (int j = 0; j < NKT / 2; ++j) {
        const int ktA = 2 * j, ktB = 2 * j + 1;
        STAGE_K(Ks0, kpA)
        LOAD_K(kpB, ktB)
        LOAD_MBITS(bB, ktB)
        __syncthreads();
        PH1_TILE(Ks0, bA)
        if (useWS) bitsWS[bitbase + (unsigned)ktA * NTHR] = (unsigned short)bA;
        STAGE_K(Ks1, kpB)
        if (j + 1 < NKT / 2) {
            LOAD_K(kpA, ktA + 2)
            LOAD_MBITS(bA, ktA + 2)
        }
        __syncthreads();
        PH1_TILE(Ks1, bB)
        if (useWS) bitsWS[bitbase + (unsigned)ktB * NTHR] = (unsigned short)bB;
    }

    float s = psum;
    s += __shfl_xor(s, 16, 64);
    s += __shfl_xor(s, 32, 64);
    const float rinv = 1.0f / s;

    f32x4 pacc[4];
    #pragma unroll
    for (int d = 0; d < 4; ++d) pacc[d] = (f32x4){0.f, 0.f, 0.f, 0.f};

    unsigned vpA[8], vpB[8];
    LOAD_K(kpA, 0)
    LOAD_V(vpA, 0)
    LOAD_BITS2(bA, 0)
    __syncthreads();

    for (int j = 0; j < NKT / 2; ++j) {
        const int ktA = 2 * j, ktB = 2 * j + 1;
        STAGE_K(Ks0, kpA)
        STAGE_V(Vt0, vpA)
        LOAD_K(kpB, ktB)
        LOAD_V(vpB, ktB)
        LOAD_BITS2(bB, ktB)
        __syncthreads();
        PH2_TILE(Ks0, Vt0, bA, ktA)
        STAGE_K(Ks1, kpB)
        STAGE_V(Vt1, vpB)
        if (j + 1 < NKT / 2) {
            LOAD_K(kpA, ktA + 2)
            LOAD_V(vpA, ktA + 2)
            LOAD_BITS2(bA, ktA + 2)
        }
        __syncthreads();
        PH2_TILE(Ks1, Vt1, bB, ktB)
    }

    #pragma unroll
    for (int df = 0; df < 4; ++df)
        #pragma unroll
        for (int r = 0; r < 4; ++r) {
            int qe = w * 16 + g * 4 + r;
            probOut[(long long)(qrowbase + qe) * D_DIM + df * 16 + c] = pacc[df][r];
        }
}

// -------------------------------------------------------------------------
extern "C" void kernel_launch(void* const* d_in, const int* in_sizes, int n_in,
                              void* d_out, int out_size, void* d_ws, size_t ws_size,
                              hipStream_t stream) {
    const float* Q = (const float*)d_in[0];
    const float* K = (const float*)d_in[1];
    const float* V = (const float*)d_in[2];
    const unsigned char* mask = (const unsigned char*)d_in[3];

    float* prob = (float*)d_out;
    float* attn = (float*)d_out + PROB_ELEMS;

    const size_t bits_bytes = (size_t)NBLK * NKT * NTHR * 2ull;   // 16.78 MB
    const size_t kbf_bytes  = 8388608ull;                          // per tensor
    int* flag = (int*)d_ws;
    unsigned short* bitsWS = (unsigned short*)((char*)d_ws + 256);
    unsigned* Kbf = (unsigned*)((char*)d_ws + 256 + bits_bytes);
    unsigned* Vtb = (unsigned*)((char*)d_ws + 256 + bits_bytes + kbf_bytes);

    const int useWS   = (ws_size >= 256 + bits_bytes) ? 1 : 0;
    const int usePrep = (ws_size >= 256 + bits_bytes + 2 * kbf_bytes) ? 1 : 0;

    mask_probe_kernel<<<1, 64, 0, stream>>>((const unsigned int*)mask, flag);
    if (usePrep) {
        kv_prep<<<(KPART + VPART) / 256, 256, 0, stream>>>(K, V, Kbf, Vtb);
        attn_fused_glds<<<NBLK, NTHR, 0, stream>>>(Q, Kbf, Vtb, mask, flag,
                                                   bitsWS, useWS, attn, prob);
    } else {
        attn_fused_reg<<<NBLK, NTHR, 0, stream>>>(Q, K, V, mask, flag,
                                                  bitsWS, useWS, attn, prob);
    }
}